// Round 3
// baseline (925.750 us; speedup 1.0000x reference)
//
#include <hip/hip_runtime.h>
#include <math.h>

#define BATCH 32
#define NN 1024
#define MM 1024
#define TT 256                  // 4 waves
#define RR 4                    // rows per thread
#define NWAVE 4
#define ELAG 64                 // extra skew per wave boundary = barrier cadence
#define TPB (MM / 4)            // 256 tile-columns per row-band
#define TILE_WORDS_PER_BATCH ((NN / 4) * (MM / 4))   // 64K words = 256KB
#define STEPS (MM + (TT - 1) + ELAG * (NWAVE - 1))   // 1024+255+192 = 1471
#define RING 256                // cross-wave boundary ring depth
#define SRING 32                // per-thread decision-word ring (padded to 33)
#define LPATH (NN + MM - 1)     // 2047

__global__ void zero_out_kernel(float* out) { out[0] = 0.0f; }

// One block per batch. Thread t owns rows [4t,4t+4). Thread t at step s
// processes column j = s - t - ELAG*(t>>6). Intra-wave boundary via
// __shfl_up (lockstep, no barrier); cross-wave boundary via a 256-deep LDS
// ring, valid because values are >=65 steps old and a barrier runs every 64
// steps. Decision words (2-bit JAX argmin([dg,up,lf]) first-min order, 4x4
// tiles) are staged in an LDS ring and flushed to global only at the
// uniform barrier steps (one vmcnt drain per 64 steps instead of per step).
__global__ __launch_bounds__(TT) void dtw_kernel(
    const float* __restrict__ preds,    // [B, NN, 4]
    const float* __restrict__ targs,    // [B, MM, 4]
    const float* __restrict__ subcoef,  // [2]
    unsigned* __restrict__ dec,         // [B, NN/4, MM/4] tile words
    float* __restrict__ out)
{
    const int b    = blockIdx.x;
    const int t    = threadIdx.x;
    const int lane = t & 63;
    const int w    = t >> 6;
    const int off  = t + ELAG * w;
    const float INF = __builtin_inff();

    __shared__ float pxA[NN], pyA[NN];          // pred coords (backtrack reuse)
    __shared__ float txy[2 * MM];               // interleaved targ coords
    __shared__ float rbuf[NWAVE - 1][RING];     // cross-wave boundary rings
    __shared__ unsigned sbuf[TT * (SRING + 1)]; // decision-word staging rings
    __shared__ unsigned path[LPATH];            // backtracked path (i<<16|j)
    __shared__ int pathLen;
    __shared__ float wsum[NWAVE];

    // Coalesced staging of features 0,1; init boundary rings to INF.
    for (int it = 0; it < NN / TT; ++it) {
        const int idx = it * TT + t;
        const float4 p4 = ((const float4*)preds)[(size_t)b * NN + idx];
        pxA[idx] = p4.x; pyA[idx] = p4.y;
        const float4 t4 = ((const float4*)targs)[(size_t)b * MM + idx];
        txy[2 * idx] = t4.x; txy[2 * idx + 1] = t4.y;
    }
    for (int it = t; it < (NWAVE - 1) * RING; it += TT)
        ((float*)rbuf)[it] = INF;
    __syncthreads();

    float pxr[RR], pyr[RR], Dp[RR];
    #pragma unroll
    for (int r = 0; r < RR; ++r) {
        pxr[r] = pxA[RR * t + r];
        pyr[r] = pyA[RR * t + r];
        Dp[r]  = INF;                    // D[row][-1]
    }
    float Dbot = INF;                    // this thread's bottom-row D at prev step
    // dg boundary for row 4t. Thread 0's first cell is the (0,0) seed: feeding
    // dg=0 reproduces the reference's inf->0 substitution exactly (argmin=0 too).
    float dgB = (t == 0) ? 0.0f : INF;
    unsigned packed = 0;
    int flushedHi = -1;
    unsigned* __restrict__ decB = dec + (size_t)b * TILE_WORDS_PER_BATCH;
    unsigned* __restrict__ decT = decB + (unsigned)t * TPB;

    for (int s = 0; s < STEPS; ++s) {
        const int j = s - off;
        // Boundary D[4t-1][j]: previous step's Dbot of thread t-1.
        float upB = __shfl_up(Dbot, 1);
        if (lane == 0) upB = (w == 0) ? INF : rbuf[w - 1][j & (RING - 1)];
        if (j >= 0 && j < MM) {
            const float txj = txy[2 * j], tyj = txy[2 * j + 1];
            float up = upB;    // D[i-1][j]
            float dg = dgB;    // D[i-1][j-1]
            unsigned mbits = 0;
            #pragma unroll
            for (int r = 0; r < RR; ++r) {
                const float dx = pxr[r] - txj;
                const float dy = pyr[r] - tyj;
                const float c  = sqrtf(dx * dx + dy * dy);
                const float lf = Dp[r];                     // D[i][j-1]
                // JAX argmin over [dg, up, lf], first-minimum tie order.
                const unsigned m = (dg <= up && dg <= lf) ? 0u
                                 : ((up <= lf) ? 1u : 2u);
                mbits |= m << (r * 8 + (j & 3) * 2);
                const float best = fminf(up, fminf(dg, lf));
                const float Dc = c + best;
                dg = lf;
                up = Dc;
                Dp[r] = Dc;
            }
            Dbot = Dp[RR - 1];
            packed |= mbits;
            if ((j & 3) == 3) {                       // tile column complete
                sbuf[t * (SRING + 1) + ((j >> 2) & (SRING - 1))] = packed;
                packed = 0;
            }
            if (lane == 63 && w < NWAVE - 1)          // expose to next wave
                rbuf[w][j & (RING - 1)] = Dbot;
        }
        dgB = upB;
        if ((s & 63) == 63) {
            // Uniform flush of completed decision words to global.
            int hi = (s - off - 3) >> 2;
            if (hi > TPB - 1) hi = TPB - 1;
            for (int c = flushedHi + 1; c <= hi; ++c)
                decT[c] = sbuf[t * (SRING + 1) + (c & (SRING - 1))];
            if (hi > flushedHi) flushedHi = hi;
            __syncthreads();
        }
    }
    // Final flush of any remaining words.
    for (int c = flushedHi + 1; c <= TPB - 1; ++c)
        decT[c] = sbuf[t * (SRING + 1) + (c & (SRING - 1))];
    __threadfence();
    __syncthreads();

    // ---- Backtrack stage 1: thread 0 walks decisions, writes path to LDS ----
    if (t == 0) {
        int i = NN - 1, jj = MM - 1;
        int n = 0;
        int ti = i >> 2, tj = jj >> 2;
        unsigned wrd = decB[ti * TPB + tj];
        while (true) {
            // Prefetch the 3 possible next tiles (clamped; unused if not taken).
            const int tjl = (tj > 0) ? tj - 1 : 0;
            const int til = (ti > 0) ? ti - 1 : 0;
            const unsigned wl = decB[ti * TPB + tjl];   // left
            const unsigned wu = decB[til * TPB + tj];   // up
            const unsigned wd = decB[til * TPB + tjl];  // diag
            bool done = false;
            while (true) {
                path[n++] = ((unsigned)i << 16) | (unsigned)jj;
                if ((i | jj) == 0) { done = true; break; }
                const unsigned m = (wrd >> (((i & 3) * 4 + (jj & 3)) * 2)) & 3u;
                i  -= (m != 2u);
                jj -= (m != 1u);
                if ((i >> 2) != ti || (jj >> 2) != tj) break;
            }
            if (done) break;
            const int nti = i >> 2, ntj = jj >> 2;
            wrd = (nti == ti) ? wl : ((ntj == tj) ? wu : wd);
            ti = nti; tj = ntj;
        }
        pathLen = n;
    }
    __syncthreads();

    // ---- Backtrack stage 2: parallel loss over path entries ----
    const float sc0 = subcoef[0];
    const float sc1 = subcoef[1];
    const int n = pathLen;
    float acc = 0.0f;
    for (int p = t; p < n; p += TT) {
        const unsigned e = path[p];
        const int i  = (int)(e >> 16);
        const int jj = (int)(e & 0xffffu);
        acc += fabsf(pxA[i] - txy[2 * jj])     * sc0
             + fabsf(pyA[i] - txy[2 * jj + 1]) * sc1;
    }
    #pragma unroll
    for (int o = 32; o > 0; o >>= 1) acc += __shfl_down(acc, o);
    if (lane == 0) wsum[w] = acc;
    __syncthreads();
    if (t == 0)
        atomicAdd(out, (wsum[0] + wsum[1]) + (wsum[2] + wsum[3]));
}

extern "C" void kernel_launch(void* const* d_in, const int* in_sizes, int n_in,
                              void* d_out, int out_size, void* d_ws, size_t ws_size,
                              hipStream_t stream) {
    const float* preds   = (const float*)d_in[0];
    const float* targs   = (const float*)d_in[1];
    const float* subcoef = (const float*)d_in[2];
    float* out = (float*)d_out;
    unsigned* dec = (unsigned*)d_ws;   // 32 * 64K * 4 = 8 MB

    zero_out_kernel<<<1, 1, 0, stream>>>(out);
    dtw_kernel<<<BATCH, TT, 0, stream>>>(preds, targs, subcoef, dec, out);
}